// Round 1
// baseline (2894.449 us; speedup 1.0000x reference)
//
#include <hip/hip_runtime.h>

typedef __bf16 bf16x8 __attribute__((ext_vector_type(8)));
typedef float  f32x4  __attribute__((ext_vector_type(4)));

#define TOKS 4096
#define DIM  1024
#define NEXP 8
#define NF   4096
#define CAP  4096   // per-expert pair capacity (worst case: all tokens pick same expert)
#define BM 128
#define BN 128
#define BK 64

__device__ __forceinline__ unsigned short f2bf(float f) {
  unsigned int u = __float_as_uint(f);
  u += 0x7FFFu + ((u >> 16) & 1u);           // round-to-nearest-even
  return (unsigned short)(u >> 16);
}
// XOR swizzle (element offset, rows of 64 bf16 = 128B): spreads bank accesses.
// Bits 3..5 of the element index -> bits 4..6 of byte offset. 16B-run preserving.
__device__ __forceinline__ int swzo(int major) {
  return ((major & 7) ^ ((major >> 3) & 7)) << 3;
}

// ---------------- routing: logits, top-2, weights, aux variance ----------------
__global__ void moe_route(const float* __restrict__ x, const float* __restrict__ Wg,
                          int* __restrict__ pairCnt, int* __restrict__ pairIdx,
                          float* __restrict__ pairWgt, float* __restrict__ auxSum)
{
  int lane = threadIdx.x & 63;
  int tok  = blockIdx.x * 4 + (threadIdx.x >> 6);
  const float* xr = x + (size_t)tok * DIM;
  float acc[8];
  #pragma unroll
  for (int e = 0; e < 8; ++e) acc[e] = 0.f;
  #pragma unroll
  for (int i = 0; i < 16; ++i) {
    int d = i * 64 + lane;
    float xv = xr[d];
    const float4* wr = (const float4*)(Wg + d * 8);
    float4 wa = wr[0], wb = wr[1];
    acc[0] += xv * wa.x; acc[1] += xv * wa.y; acc[2] += xv * wa.z; acc[3] += xv * wa.w;
    acc[4] += xv * wb.x; acc[5] += xv * wb.y; acc[6] += xv * wb.z; acc[7] += xv * wb.w;
  }
  #pragma unroll
  for (int e = 0; e < 8; ++e) {
    float v = acc[e];
    #pragma unroll
    for (int off = 32; off; off >>= 1) v += __shfl_xor(v, off);
    acc[e] = v;
  }
  if (lane == 0) {
    int e1 = 0; float l1 = acc[0];
    #pragma unroll
    for (int e = 1; e < 8; ++e) if (acc[e] > l1) { l1 = acc[e]; e1 = e; }
    int e2 = -1; float l2 = -3.4e38f;
    #pragma unroll
    for (int e = 0; e < 8; ++e) if (e != e1 && acc[e] > l2) { l2 = acc[e]; e2 = e; }
    // softmax -> top2 -> renorm  ==  2-way softmax over (l1,l2)
    float r  = expf(l2 - l1);
    float w1 = 1.f / (1.f + r);
    float w2 = r / (1.f + r);
    int s1 = atomicAdd(&pairCnt[e1], 1);
    pairIdx[e1 * CAP + s1] = tok * 2;     pairWgt[e1 * CAP + s1] = w1;
    int s2 = atomicAdd(&pairCnt[e2], 1);
    pairIdx[e2 * CAP + s2] = tok * 2 + 1; pairWgt[e2 * CAP + s2] = w2;
    // unbiased variance of the 8 logits
    float m = 0.f;
    #pragma unroll
    for (int e = 0; e < 8; ++e) m += acc[e];
    m *= 0.125f;
    float v = 0.f;
    #pragma unroll
    for (int e = 0; e < 8; ++e) { float dd = acc[e] - m; v += dd * dd; }
    atomicAdd(auxSum, v * (1.f / 7.f));
  }
}

__global__ void moe_aux_final(const float* __restrict__ auxSum, float* __restrict__ outScalar) {
  *outScalar = auxSum[0] * (1.f / (float)TOKS);
}

// ---------------- FFN1: h = silu(x@W1[e]) * (x@W3[e])  (grouped by expert) ----------------
__global__ __launch_bounds__(512) void moe_ffn1(
    const float* __restrict__ x, const float* __restrict__ W1, const float* __restrict__ W3,
    const int* __restrict__ pairCnt, const int* __restrict__ pairIdx,
    unsigned short* __restrict__ hbuf)
{
  int e   = blockIdx.z;
  int cnt = pairCnt[e];
  int m0  = blockIdx.x * BM;
  if (m0 >= cnt) return;
  int n0  = blockIdx.y * BN;            // F offset
  __shared__ __attribute__((aligned(16))) unsigned short As[BM * BK];
  __shared__ __attribute__((aligned(16))) unsigned short B1s[BN * BK];
  __shared__ __attribute__((aligned(16))) unsigned short B3s[BN * BK];
  __shared__ int rowPid[BM];
  int tid = threadIdx.x;
  if (tid < BM) {
    int gi = m0 + tid;
    rowPid[tid] = (gi < cnt) ? pairIdx[e * CAP + gi] : -1;
  }
  const float* W1e = W1 + (size_t)e * DIM * NF;
  const float* W3e = W3 + (size_t)e * DIM * NF;
  f32x4 zero = {0.f, 0.f, 0.f, 0.f};
  f32x4 acc1[2][4], acc2[2][4];
  #pragma unroll
  for (int mi = 0; mi < 2; ++mi)
    #pragma unroll
    for (int ni = 0; ni < 4; ++ni) { acc1[mi][ni] = zero; acc2[mi][ni] = zero; }
  int lane = tid & 63, wid = tid >> 6;
  int wm = (wid >> 1) * 32, wn = (wid & 1) * 64;

  for (int kt = 0; kt < DIM; kt += BK) {
    __syncthreads();
    // stage A: gathered x rows, fp32 -> bf16
    #pragma unroll
    for (int it = 0; it < 4; ++it) {
      int row = it * 32 + (tid >> 4);
      int dq  = tid & 15;
      int pid = rowPid[row];
      int tk  = (pid >= 0) ? (pid >> 1) : 0;
      float4 v = *(const float4*)(x + (size_t)tk * DIM + kt + dq * 4);
      ushort4 b; b.x = f2bf(v.x); b.y = f2bf(v.y); b.z = f2bf(v.z); b.w = f2bf(v.w);
      *(ushort4*)(&As[row * BK + ((dq * 4) ^ swzo(row))]) = b;
    }
    // stage B1/B3: transposed [f][d] (coalesced global reads along f)
    #pragma unroll
    for (int it = 0; it < 4; ++it) {
      int d  = it * 16 + (tid >> 5);
      int fq = tid & 31;
      size_t go = (size_t)(kt + d) * NF + n0 + fq * 4;
      float4 v1 = *(const float4*)(W1e + go);
      float4 v3 = *(const float4*)(W3e + go);
      const float* p1 = (const float*)&v1;
      const float* p3 = (const float*)&v3;
      #pragma unroll
      for (int i = 0; i < 4; ++i) {
        int f   = fq * 4 + i;
        int idx = f * BK + (d ^ swzo(f));
        B1s[idx] = f2bf(p1[i]);
        B3s[idx] = f2bf(p3[i]);
      }
    }
    __syncthreads();
    #pragma unroll
    for (int ks = 0; ks < 2; ++ks) {
      int kb = ks * 32 + ((lane >> 4) << 3);
      bf16x8 af[2];
      #pragma unroll
      for (int mi = 0; mi < 2; ++mi) {
        int row = wm + mi * 16 + (lane & 15);
        af[mi] = *(const bf16x8*)(&As[row * BK + (kb ^ swzo(row))]);
      }
      #pragma unroll
      for (int ni = 0; ni < 4; ++ni) {
        int f = wn + ni * 16 + (lane & 15);
        bf16x8 b1 = *(const bf16x8*)(&B1s[f * BK + (kb ^ swzo(f))]);
        bf16x8 b3 = *(const bf16x8*)(&B3s[f * BK + (kb ^ swzo(f))]);
        #pragma unroll
        for (int mi = 0; mi < 2; ++mi) {
          acc1[mi][ni] = __builtin_amdgcn_mfma_f32_16x16x32_bf16(af[mi], b1, acc1[mi][ni], 0, 0, 0);
          acc2[mi][ni] = __builtin_amdgcn_mfma_f32_16x16x32_bf16(af[mi], b3, acc2[mi][ni], 0, 0, 0);
        }
      }
    }
  }
  // epilogue: h = silu(a) * g -> bf16
  #pragma unroll
  for (int mi = 0; mi < 2; ++mi) {
    #pragma unroll
    for (int r = 0; r < 4; ++r) {
      int row = wm + mi * 16 + ((lane >> 4) << 2) + r;
      int pid = rowPid[row];
      if (pid < 0) continue;
      size_t hb = (size_t)pid * NF + n0 + wn + (lane & 15);
      #pragma unroll
      for (int ni = 0; ni < 4; ++ni) {
        float a = acc1[mi][ni][r];
        float g = acc2[mi][ni][r];
        float s = 1.f / (1.f + __expf(-a));
        hbuf[hb + ni * 16] = f2bf(a * s * g);
      }
    }
  }
}

// ---------------- FFN2: out[tok] += w * (h @ W2[e]) ----------------
__global__ __launch_bounds__(512) void moe_ffn2(
    const unsigned short* __restrict__ hbuf, const float* __restrict__ W2,
    const int* __restrict__ pairCnt, const int* __restrict__ pairIdx,
    const float* __restrict__ pairWgt, float* __restrict__ out)
{
  int e   = blockIdx.z;
  int cnt = pairCnt[e];
  int m0  = blockIdx.x * BM;
  if (m0 >= cnt) return;
  int n0  = blockIdx.y * BN;            // D offset
  __shared__ __attribute__((aligned(16))) unsigned short As[BM * BK];
  __shared__ __attribute__((aligned(16))) unsigned short Bs[BN * BK];
  __shared__ int   rowPid[BM];
  __shared__ float rowW[BM];
  int tid = threadIdx.x;
  if (tid < BM) {
    int gi = m0 + tid;
    if (gi < cnt) { rowPid[tid] = pairIdx[e * CAP + gi]; rowW[tid] = pairWgt[e * CAP + gi]; }
    else          { rowPid[tid] = -1;                    rowW[tid] = 0.f; }
  }
  const float* W2e = W2 + (size_t)e * NF * DIM;
  f32x4 zero = {0.f, 0.f, 0.f, 0.f};
  f32x4 acc[2][4];
  #pragma unroll
  for (int mi = 0; mi < 2; ++mi)
    #pragma unroll
    for (int ni = 0; ni < 4; ++ni) acc[mi][ni] = zero;
  int lane = tid & 63, wid = tid >> 6;
  int wm = (wid >> 1) * 32, wn = (wid & 1) * 64;

  for (int kt = 0; kt < NF; kt += BK) {
    __syncthreads();
    // stage A: gathered h rows (already bf16, 16B chunks)
    #pragma unroll
    for (int it = 0; it < 2; ++it) {
      int row = it * 64 + (tid >> 3);
      int c8  = tid & 7;
      int pid = rowPid[row];
      int pr  = (pid >= 0) ? pid : 0;
      uint4 v = *(const uint4*)(hbuf + (size_t)pr * NF + kt + c8 * 8);
      *(uint4*)(&As[row * BK + ((c8 * 8) ^ swzo(row))]) = v;
    }
    // stage B: W2 transposed [d][f]
    #pragma unroll
    for (int it = 0; it < 4; ++it) {
      int fk = it * 16 + (tid >> 5);
      int dq = tid & 31;
      float4 v = *(const float4*)(W2e + (size_t)(kt + fk) * DIM + n0 + dq * 4);
      const float* p = (const float*)&v;
      #pragma unroll
      for (int i = 0; i < 4; ++i) {
        int dc = dq * 4 + i;
        Bs[dc * BK + (fk ^ swzo(dc))] = f2bf(p[i]);
      }
    }
    __syncthreads();
    #pragma unroll
    for (int ks = 0; ks < 2; ++ks) {
      int kb = ks * 32 + ((lane >> 4) << 3);
      bf16x8 af[2];
      #pragma unroll
      for (int mi = 0; mi < 2; ++mi) {
        int row = wm + mi * 16 + (lane & 15);
        af[mi] = *(const bf16x8*)(&As[row * BK + (kb ^ swzo(row))]);
      }
      #pragma unroll
      for (int ni = 0; ni < 4; ++ni) {
        int dc = wn + ni * 16 + (lane & 15);
        bf16x8 b = *(const bf16x8*)(&Bs[dc * BK + (kb ^ swzo(dc))]);
        #pragma unroll
        for (int mi = 0; mi < 2; ++mi)
          acc[mi][ni] = __builtin_amdgcn_mfma_f32_16x16x32_bf16(af[mi], b, acc[mi][ni], 0, 0, 0);
      }
    }
  }
  #pragma unroll
  for (int mi = 0; mi < 2; ++mi) {
    #pragma unroll
    for (int r = 0; r < 4; ++r) {
      int row = wm + mi * 16 + ((lane >> 4) << 2) + r;
      int pid = rowPid[row];
      if (pid < 0) continue;
      float w = rowW[row];
      float* op = out + (size_t)(pid >> 1) * DIM + n0 + wn + (lane & 15);
      #pragma unroll
      for (int ni = 0; ni < 4; ++ni)
        atomicAdd(op + ni * 16, w * acc[mi][ni][r]);
    }
  }
}

extern "C" void kernel_launch(void* const* d_in, const int* in_sizes, int n_in,
                              void* d_out, int out_size, void* d_ws, size_t ws_size,
                              hipStream_t stream)
{
  const float* x  = (const float*)d_in[0];
  const float* Wg = (const float*)d_in[1];
  const float* W1 = (const float*)d_in[2];
  const float* W2 = (const float*)d_in[3];
  const float* W3 = (const float*)d_in[4];
  float* out = (float*)d_out;
  char*  ws  = (char*)d_ws;
  // ws layout: [0,32) pairCnt, [64,68) auxSum, [4K,132K) pairIdx, [256K,384K) pairWgt, [1M,1M+64M) h(bf16)
  int*   pairCnt = (int*)ws;
  float* auxSum  = (float*)(ws + 64);
  int*   pairIdx = (int*)(ws + 4096);
  float* pairWgt = (float*)(ws + 262144);
  unsigned short* hbuf = (unsigned short*)(ws + (1 << 20));

  hipMemsetAsync(ws, 0, 128, stream);                                   // counters + aux
  hipMemsetAsync(d_out, 0, (size_t)out_size * sizeof(float), stream);   // out accumulated atomically
  moe_route<<<TOKS / 4, 256, 0, stream>>>(x, Wg, pairCnt, pairIdx, pairWgt, auxSum);
  moe_aux_final<<<1, 1, 0, stream>>>(auxSum, out + (out_size - 1));
  moe_ffn1<<<dim3(TOKS / BM, NF / BN, NEXP), 512, 0, stream>>>(x, W1, W3, pairCnt, pairIdx, hbuf);
  moe_ffn2<<<dim3(TOKS / BM, DIM / BN, NEXP), 512, 0, stream>>>(hbuf, W2, pairCnt, pairIdx, pairWgt, out);
}

// Round 2
// 618.348 us; speedup vs baseline: 4.6809x; 4.6809x over previous
//
#include <hip/hip_runtime.h>

typedef __bf16 bf16x8 __attribute__((ext_vector_type(8)));
typedef float  f32x4  __attribute__((ext_vector_type(4)));

#define TOKS 4096
#define DIM  1024
#define NEXP 8
#define NF   4096
#define CAP  4096   // per-expert pair capacity
#define BM 128
#define BN 128
#define BK 64

__device__ __forceinline__ unsigned short f2bf(float f) {
  unsigned int u = __float_as_uint(f);
  u += 0x7FFFu + ((u >> 16) & 1u);           // round-to-nearest-even
  return (unsigned short)(u >> 16);
}
// old swizzle (fallback kernels)
__device__ __forceinline__ int swzo(int major) {
  return ((major & 7) ^ ((major >> 3) & 7)) << 3;
}
// new: XOR 16B-chunk index with row&7; arg/result in elements (8 bf16 chunks)
__device__ __forceinline__ int swz8(int row, int chunk) {
  return (chunk ^ (row & 7)) << 3;
}

// ---------------- routing ----------------
__global__ void moe_route(const float* __restrict__ x, const float* __restrict__ Wg,
                          int* __restrict__ pairCnt, int* __restrict__ pairIdx,
                          float* __restrict__ pairWgt, float* __restrict__ auxSum)
{
  int lane = threadIdx.x & 63;
  int tok  = blockIdx.x * 4 + (threadIdx.x >> 6);
  const float* xr = x + (size_t)tok * DIM;
  float acc[8];
  #pragma unroll
  for (int e = 0; e < 8; ++e) acc[e] = 0.f;
  #pragma unroll
  for (int i = 0; i < 16; ++i) {
    int d = i * 64 + lane;
    float xv = xr[d];
    const float4* wr = (const float4*)(Wg + d * 8);
    float4 wa = wr[0], wb = wr[1];
    acc[0] += xv * wa.x; acc[1] += xv * wa.y; acc[2] += xv * wa.z; acc[3] += xv * wa.w;
    acc[4] += xv * wb.x; acc[5] += xv * wb.y; acc[6] += xv * wb.z; acc[7] += xv * wb.w;
  }
  #pragma unroll
  for (int e = 0; e < 8; ++e) {
    float v = acc[e];
    #pragma unroll
    for (int off = 32; off; off >>= 1) v += __shfl_xor(v, off);
    acc[e] = v;
  }
  if (lane == 0) {
    int e1 = 0; float l1 = acc[0];
    #pragma unroll
    for (int e = 1; e < 8; ++e) if (acc[e] > l1) { l1 = acc[e]; e1 = e; }
    int e2 = -1; float l2 = -3.4e38f;
    #pragma unroll
    for (int e = 0; e < 8; ++e) if (e != e1 && acc[e] > l2) { l2 = acc[e]; e2 = e; }
    float r  = expf(l2 - l1);
    float w1 = 1.f / (1.f + r);
    float w2 = r / (1.f + r);
    int s1 = atomicAdd(&pairCnt[e1], 1);
    pairIdx[e1 * CAP + s1] = tok * 2;     pairWgt[e1 * CAP + s1] = w1;
    int s2 = atomicAdd(&pairCnt[e2], 1);
    pairIdx[e2 * CAP + s2] = tok * 2 + 1; pairWgt[e2 * CAP + s2] = w2;
    float m = 0.f;
    #pragma unroll
    for (int e = 0; e < 8; ++e) m += acc[e];
    m *= 0.125f;
    float v = 0.f;
    #pragma unroll
    for (int e = 0; e < 8; ++e) { float dd = acc[e] - m; v += dd * dd; }
    atomicAdd(auxSum, v * (1.f / 7.f));
  }
}

__global__ void moe_aux_final(const float* __restrict__ auxSum, float* __restrict__ outScalar) {
  *outScalar = auxSum[0] * (1.f / (float)TOKS);
}

// ---------------- weight prep: fp32 [E][R][C] -> bf16 [E][C][R] ----------------
__global__ __launch_bounds__(256) void cvt_transpose(
    const float* __restrict__ in, unsigned short* __restrict__ outp, int R, int C)
{
  __shared__ unsigned short tile[64 * 72];
  int e  = blockIdx.z;
  int r0 = blockIdx.x * 64, c0 = blockIdx.y * 64;
  const float*    ine  = in   + (size_t)e * R * C;
  unsigned short* oute = outp + (size_t)e * R * C;
  int t = threadIdx.x;
  int r = t >> 2, cs = (t & 3) * 16;
  const float4* src = (const float4*)(ine + (size_t)(r0 + r) * C + c0 + cs);
  #pragma unroll
  for (int j = 0; j < 4; ++j) {
    float4 v = src[j];
    tile[(cs + j * 4 + 0) * 72 + r] = f2bf(v.x);
    tile[(cs + j * 4 + 1) * 72 + r] = f2bf(v.y);
    tile[(cs + j * 4 + 2) * 72 + r] = f2bf(v.z);
    tile[(cs + j * 4 + 3) * 72 + r] = f2bf(v.w);
  }
  __syncthreads();
  int c = t >> 2, rs = (t & 3) * 16;
  uint4 o0 = *(const uint4*)&tile[c * 72 + rs];
  uint4 o1 = *(const uint4*)&tile[c * 72 + rs + 8];
  unsigned short* dst = oute + (size_t)(c0 + c) * R + r0 + rs;
  *(uint4*)dst       = o0;
  *(uint4*)(dst + 8) = o1;
}

// ---------------- fast FFN1: h = silu(x@W1) * (x@W3), bf16 pre-transposed weights ----------------
__global__ __launch_bounds__(512) void moe_ffn1_f(
    const float* __restrict__ x, const unsigned short* __restrict__ W1T,
    const unsigned short* __restrict__ W3T,
    const int* __restrict__ pairCnt, const int* __restrict__ pairIdx,
    unsigned short* __restrict__ hbuf)
{
  // bid bits: [0:3)=n_low(XCD), [3:8)=m, [8:10)=n_high, [10:13)=e
  int bid = blockIdx.x;
  int m_t = (bid >> 3) & 31;
  int n_t = (bid & 7) | (((bid >> 8) & 3) << 3);
  int e   = bid >> 10;
  int cnt = pairCnt[e];
  int m0  = m_t * BM;
  if (m0 >= cnt) return;
  int n0  = n_t * BN;
  __shared__ __attribute__((aligned(16))) unsigned short As[BM * BK];
  __shared__ __attribute__((aligned(16))) unsigned short B1s[BN * BK];
  __shared__ __attribute__((aligned(16))) unsigned short B3s[BN * BK];
  __shared__ int rowPid[BM];
  int tid = threadIdx.x;
  if (tid < BM) {
    int gi = m0 + tid;
    rowPid[tid] = (gi < cnt) ? pairIdx[e * CAP + gi] : -1;
  }
  const unsigned short* W1e = W1T + (size_t)e * NF * DIM + (size_t)n0 * DIM;
  const unsigned short* W3e = W3T + (size_t)e * NF * DIM + (size_t)n0 * DIM;
  f32x4 zero = {0.f, 0.f, 0.f, 0.f};
  f32x4 acc1[2][4], acc2[2][4];
  #pragma unroll
  for (int mi = 0; mi < 2; ++mi)
    #pragma unroll
    for (int ni = 0; ni < 4; ++ni) { acc1[mi][ni] = zero; acc2[mi][ni] = zero; }
  int lane = tid & 63, wid = tid >> 6;
  int wm = (wid >> 1) * 32, wn = (wid & 1) * 64;

  int sr = tid >> 2;              // staging row (0..127)
  int sc = (tid & 3) * 16;        // 16 elements along K
  int co = sc >> 3;               // 16B chunk index (0,2,4,6)
  __syncthreads();                // rowPid visible
  int pidA = rowPid[sr];
  const float* xrow = x + (size_t)((pidA >= 0) ? (pidA >> 1) : 0) * DIM + sc;
  const unsigned short* b1row = W1e + (size_t)sr * DIM + sc;
  const unsigned short* b3row = W3e + (size_t)sr * DIM + sc;

  for (int kt = 0; kt < DIM; kt += BK) {
    // stage A (fp32 -> bf16)
    {
      const float4* xs = (const float4*)(xrow + kt);
      float4 v0 = xs[0], v1 = xs[1], v2 = xs[2], v3 = xs[3];
      union { unsigned short u[8]; uint4 q; } p0, p1;
      p0.u[0]=f2bf(v0.x); p0.u[1]=f2bf(v0.y); p0.u[2]=f2bf(v0.z); p0.u[3]=f2bf(v0.w);
      p0.u[4]=f2bf(v1.x); p0.u[5]=f2bf(v1.y); p0.u[6]=f2bf(v1.z); p0.u[7]=f2bf(v1.w);
      p1.u[0]=f2bf(v2.x); p1.u[1]=f2bf(v2.y); p1.u[2]=f2bf(v2.z); p1.u[3]=f2bf(v2.w);
      p1.u[4]=f2bf(v3.x); p1.u[5]=f2bf(v3.y); p1.u[6]=f2bf(v3.z); p1.u[7]=f2bf(v3.w);
      *(uint4*)&As[sr * BK + swz8(sr, co)]     = p0.q;
      *(uint4*)&As[sr * BK + swz8(sr, co + 1)] = p1.q;
    }
    // stage B1/B3 (bf16 direct)
    {
      uint4 q0 = *(const uint4*)(b1row + kt);
      uint4 q1 = *(const uint4*)(b1row + kt + 8);
      uint4 r0 = *(const uint4*)(b3row + kt);
      uint4 r1 = *(const uint4*)(b3row + kt + 8);
      *(uint4*)&B1s[sr * BK + swz8(sr, co)]     = q0;
      *(uint4*)&B1s[sr * BK + swz8(sr, co + 1)] = q1;
      *(uint4*)&B3s[sr * BK + swz8(sr, co)]     = r0;
      *(uint4*)&B3s[sr * BK + swz8(sr, co + 1)] = r1;
    }
    __syncthreads();
    #pragma unroll
    for (int ks = 0; ks < 2; ++ks) {
      int kc = ks * 4 + (lane >> 4);   // 16B chunk along K
      bf16x8 af[2];
      #pragma unroll
      for (int mi = 0; mi < 2; ++mi) {
        int row = wm + mi * 16 + (lane & 15);
        af[mi] = *(const bf16x8*)(&As[row * BK + swz8(row, kc)]);
      }
      #pragma unroll
      for (int ni = 0; ni < 4; ++ni) {
        int f = wn + ni * 16 + (lane & 15);
        bf16x8 b1 = *(const bf16x8*)(&B1s[f * BK + swz8(f, kc)]);
        bf16x8 b3 = *(const bf16x8*)(&B3s[f * BK + swz8(f, kc)]);
        #pragma unroll
        for (int mi = 0; mi < 2; ++mi) {
          acc1[mi][ni] = __builtin_amdgcn_mfma_f32_16x16x32_bf16(af[mi], b1, acc1[mi][ni], 0, 0, 0);
          acc2[mi][ni] = __builtin_amdgcn_mfma_f32_16x16x32_bf16(af[mi], b3, acc2[mi][ni], 0, 0, 0);
        }
      }
    }
    __syncthreads();
  }
  #pragma unroll
  for (int mi = 0; mi < 2; ++mi) {
    #pragma unroll
    for (int r = 0; r < 4; ++r) {
      int row = wm + mi * 16 + ((lane >> 4) << 2) + r;
      int pid = rowPid[row];
      if (pid < 0) continue;
      size_t hb = (size_t)pid * NF + n0 + wn + (lane & 15);
      #pragma unroll
      for (int ni = 0; ni < 4; ++ni) {
        float a = acc1[mi][ni][r];
        float g = acc2[mi][ni][r];
        float s = 1.f / (1.f + __expf(-a));
        hbuf[hb + ni * 16] = f2bf(a * s * g);
      }
    }
  }
}

// ---------------- fast FFN2: out[tok] += w * (h @ W2), bf16 pre-transposed W2 ----------------
__global__ __launch_bounds__(512) void moe_ffn2_f(
    const unsigned short* __restrict__ hbuf, const unsigned short* __restrict__ W2T,
    const int* __restrict__ pairCnt, const int* __restrict__ pairIdx,
    const float* __restrict__ pairWgt, float* __restrict__ out)
{
  // bid bits: [0:3)=n(XCD), [3:8)=m, [8:11)=e
  int bid = blockIdx.x;
  int n_t = bid & 7;
  int m_t = (bid >> 3) & 31;
  int e   = bid >> 8;
  int cnt = pairCnt[e];
  int m0  = m_t * BM;
  if (m0 >= cnt) return;
  int n0  = n_t * BN;
  __shared__ __attribute__((aligned(16))) unsigned short As[BM * BK];
  __shared__ __attribute__((aligned(16))) unsigned short Bs[BN * BK];
  __shared__ int   rowPid[BM];
  __shared__ float rowW[BM];
  int tid = threadIdx.x;
  if (tid < BM) {
    int gi = m0 + tid;
    if (gi < cnt) { rowPid[tid] = pairIdx[e * CAP + gi]; rowW[tid] = pairWgt[e * CAP + gi]; }
    else          { rowPid[tid] = -1;                    rowW[tid] = 0.f; }
  }
  const unsigned short* W2e = W2T + (size_t)e * DIM * NF + (size_t)n0 * NF;
  f32x4 zero = {0.f, 0.f, 0.f, 0.f};
  f32x4 acc[2][4];
  #pragma unroll
  for (int mi = 0; mi < 2; ++mi)
    #pragma unroll
    for (int ni = 0; ni < 4; ++ni) acc[mi][ni] = zero;
  int lane = tid & 63, wid = tid >> 6;
  int wm = (wid >> 1) * 32, wn = (wid & 1) * 64;

  int sr = tid >> 2;
  int sc = (tid & 3) * 16;
  int co = sc >> 3;
  __syncthreads();
  int pidA = rowPid[sr];
  const unsigned short* hrow = hbuf + (size_t)((pidA >= 0) ? pidA : 0) * NF + sc;
  const unsigned short* brow = W2e + (size_t)sr * NF + sc;

  for (int kt = 0; kt < NF; kt += BK) {
    {
      uint4 a0 = *(const uint4*)(hrow + kt);
      uint4 a1 = *(const uint4*)(hrow + kt + 8);
      uint4 q0 = *(const uint4*)(brow + kt);
      uint4 q1 = *(const uint4*)(brow + kt + 8);
      *(uint4*)&As[sr * BK + swz8(sr, co)]     = a0;
      *(uint4*)&As[sr * BK + swz8(sr, co + 1)] = a1;
      *(uint4*)&Bs[sr * BK + swz8(sr, co)]     = q0;
      *(uint4*)&Bs[sr * BK + swz8(sr, co + 1)] = q1;
    }
    __syncthreads();
    #pragma unroll
    for (int ks = 0; ks < 2; ++ks) {
      int kc = ks * 4 + (lane >> 4);
      bf16x8 af[2];
      #pragma unroll
      for (int mi = 0; mi < 2; ++mi) {
        int row = wm + mi * 16 + (lane & 15);
        af[mi] = *(const bf16x8*)(&As[row * BK + swz8(row, kc)]);
      }
      #pragma unroll
      for (int ni = 0; ni < 4; ++ni) {
        int dc = wn + ni * 16 + (lane & 15);
        bf16x8 b = *(const bf16x8*)(&Bs[dc * BK + swz8(dc, kc)]);
        #pragma unroll
        for (int mi = 0; mi < 2; ++mi)
          acc[mi][ni] = __builtin_amdgcn_mfma_f32_16x16x32_bf16(af[mi], b, acc[mi][ni], 0, 0, 0);
      }
    }
    __syncthreads();
  }
  #pragma unroll
  for (int mi = 0; mi < 2; ++mi) {
    #pragma unroll
    for (int r = 0; r < 4; ++r) {
      int row = wm + mi * 16 + ((lane >> 4) << 2) + r;
      int pid = rowPid[row];
      if (pid < 0) continue;
      float w = rowW[row];
      float* op = out + (size_t)(pid >> 1) * DIM + n0 + wn + (lane & 15);
      #pragma unroll
      for (int ni = 0; ni < 4; ++ni)
        atomicAdd(op + ni * 16, w * acc[mi][ni][r]);
    }
  }
}

// ================= fallback (round-1, fp32 weights in-kernel) =================
__global__ __launch_bounds__(512) void moe_ffn1(
    const float* __restrict__ x, const float* __restrict__ W1, const float* __restrict__ W3,
    const int* __restrict__ pairCnt, const int* __restrict__ pairIdx,
    unsigned short* __restrict__ hbuf)
{
  int e   = blockIdx.z;
  int cnt = pairCnt[e];
  int m0  = blockIdx.x * BM;
  if (m0 >= cnt) return;
  int n0  = blockIdx.y * BN;
  __shared__ __attribute__((aligned(16))) unsigned short As[BM * BK];
  __shared__ __attribute__((aligned(16))) unsigned short B1s[BN * BK];
  __shared__ __attribute__((aligned(16))) unsigned short B3s[BN * BK];
  __shared__ int rowPid[BM];
  int tid = threadIdx.x;
  if (tid < BM) {
    int gi = m0 + tid;
    rowPid[tid] = (gi < cnt) ? pairIdx[e * CAP + gi] : -1;
  }
  const float* W1e = W1 + (size_t)e * DIM * NF;
  const float* W3e = W3 + (size_t)e * DIM * NF;
  f32x4 zero = {0.f, 0.f, 0.f, 0.f};
  f32x4 acc1[2][4], acc2[2][4];
  #pragma unroll
  for (int mi = 0; mi < 2; ++mi)
    #pragma unroll
    for (int ni = 0; ni < 4; ++ni) { acc1[mi][ni] = zero; acc2[mi][ni] = zero; }
  int lane = tid & 63, wid = tid >> 6;
  int wm = (wid >> 1) * 32, wn = (wid & 1) * 64;

  for (int kt = 0; kt < DIM; kt += BK) {
    __syncthreads();
    #pragma unroll
    for (int it = 0; it < 4; ++it) {
      int row = it * 32 + (tid >> 4);
      int dq  = tid & 15;
      int pid = rowPid[row];
      int tk  = (pid >= 0) ? (pid >> 1) : 0;
      float4 v = *(const float4*)(x + (size_t)tk * DIM + kt + dq * 4);
      ushort4 b; b.x = f2bf(v.x); b.y = f2bf(v.y); b.z = f2bf(v.z); b.w = f2bf(v.w);
      *(ushort4*)(&As[row * BK + ((dq * 4) ^ swzo(row))]) = b;
    }
    #pragma unroll
    for (int it = 0; it < 4; ++it) {
      int d  = it * 16 + (tid >> 5);
      int fq = tid & 31;
      size_t go = (size_t)(kt + d) * NF + n0 + fq * 4;
      float4 v1 = *(const float4*)(W1e + go);
      float4 v3 = *(const float4*)(W3e + go);
      const float* p1 = (const float*)&v1;
      const float* p3 = (const float*)&v3;
      #pragma unroll
      for (int i = 0; i < 4; ++i) {
        int f   = fq * 4 + i;
        int idx = f * BK + (d ^ swzo(f));
        B1s[idx] = f2bf(p1[i]);
        B3s[idx] = f2bf(p3[i]);
      }
    }
    __syncthreads();
    #pragma unroll
    for (int ks = 0; ks < 2; ++ks) {
      int kb = ks * 32 + ((lane >> 4) << 3);
      bf16x8 af[2];
      #pragma unroll
      for (int mi = 0; mi < 2; ++mi) {
        int row = wm + mi * 16 + (lane & 15);
        af[mi] = *(const bf16x8*)(&As[row * BK + (kb ^ swzo(row))]);
      }
      #pragma unroll
      for (int ni = 0; ni < 4; ++ni) {
        int f = wn + ni * 16 + (lane & 15);
        bf16x8 b1 = *(const bf16x8*)(&B1s[f * BK + (kb ^ swzo(f))]);
        bf16x8 b3 = *(const bf16x8*)(&B3s[f * BK + (kb ^ swzo(f))]);
        #pragma unroll
        for (int mi = 0; mi < 2; ++mi) {
          acc1[mi][ni] = __builtin_amdgcn_mfma_f32_16x16x32_bf16(af[mi], b1, acc1[mi][ni], 0, 0, 0);
          acc2[mi][ni] = __builtin_amdgcn_mfma_f32_16x16x32_bf16(af[mi], b3, acc2[mi][ni], 0, 0, 0);
        }
      }
    }
  }
  #pragma unroll
  for (int mi = 0; mi < 2; ++mi) {
    #pragma unroll
    for (int r = 0; r < 4; ++r) {
      int row = wm + mi * 16 + ((lane >> 4) << 2) + r;
      int pid = rowPid[row];
      if (pid < 0) continue;
      size_t hb = (size_t)pid * NF + n0 + wn + (lane & 15);
      #pragma unroll
      for (int ni = 0; ni < 4; ++ni) {
        float a = acc1[mi][ni][r];
        float g = acc2[mi][ni][r];
        float s = 1.f / (1.f + __expf(-a));
        hbuf[hb + ni * 16] = f2bf(a * s * g);
      }
    }
  }
}

__global__ __launch_bounds__(512) void moe_ffn2(
    const unsigned short* __restrict__ hbuf, const float* __restrict__ W2,
    const int* __restrict__ pairCnt, const int* __restrict__ pairIdx,
    const float* __restrict__ pairWgt, float* __restrict__ out)
{
  int e   = blockIdx.z;
  int cnt = pairCnt[e];
  int m0  = blockIdx.x * BM;
  if (m0 >= cnt) return;
  int n0  = blockIdx.y * BN;
  __shared__ __attribute__((aligned(16))) unsigned short As[BM * BK];
  __shared__ __attribute__((aligned(16))) unsigned short Bs[BN * BK];
  __shared__ int   rowPid[BM];
  __shared__ float rowW[BM];
  int tid = threadIdx.x;
  if (tid < BM) {
    int gi = m0 + tid;
    if (gi < cnt) { rowPid[tid] = pairIdx[e * CAP + gi]; rowW[tid] = pairWgt[e * CAP + gi]; }
    else          { rowPid[tid] = -1;                    rowW[tid] = 0.f; }
  }
  const float* W2e = W2 + (size_t)e * NF * DIM;
  f32x4 zero = {0.f, 0.f, 0.f, 0.f};
  f32x4 acc[2][4];
  #pragma unroll
  for (int mi = 0; mi < 2; ++mi)
    #pragma unroll
    for (int ni = 0; ni < 4; ++ni) acc[mi][ni] = zero;
  int lane = tid & 63, wid = tid >> 6;
  int wm = (wid >> 1) * 32, wn = (wid & 1) * 64;

  for (int kt = 0; kt < NF; kt += BK) {
    __syncthreads();
    #pragma unroll
    for (int it = 0; it < 2; ++it) {
      int row = it * 64 + (tid >> 3);
      int c8  = tid & 7;
      int pid = rowPid[row];
      int pr  = (pid >= 0) ? pid : 0;
      uint4 v = *(const uint4*)(hbuf + (size_t)pr * NF + kt + c8 * 8);
      *(uint4*)(&As[row * BK + ((c8 * 8) ^ swzo(row))]) = v;
    }
    #pragma unroll
    for (int it = 0; it < 4; ++it) {
      int fk = it * 16 + (tid >> 5);
      int dq = tid & 31;
      float4 v = *(const float4*)(W2e + (size_t)(kt + fk) * DIM + n0 + dq * 4);
      const float* p = (const float*)&v;
      #pragma unroll
      for (int i = 0; i < 4; ++i) {
        int dc = dq * 4 + i;
        Bs[dc * BK + (fk ^ swzo(dc))] = f2bf(p[i]);
      }
    }
    __syncthreads();
    #pragma unroll
    for (int ks = 0; ks < 2; ++ks) {
      int kb = ks * 32 + ((lane >> 4) << 3);
      bf16x8 af[2];
      #pragma unroll
      for (int mi = 0; mi < 2; ++mi) {
        int row = wm + mi * 16 + (lane & 15);
        af[mi] = *(const bf16x8*)(&As[row * BK + (kb ^ swzo(row))]);
      }
      #pragma unroll
      for (int ni = 0; ni < 4; ++ni) {
        int dc = wn + ni * 16 + (lane & 15);
        bf16x8 b = *(const bf16x8*)(&Bs[dc * BK + (kb ^ swzo(dc))]);
        #pragma unroll
        for (int mi = 0; mi < 2; ++mi)
          acc[mi][ni] = __builtin_amdgcn_mfma_f32_16x16x32_bf16(af[mi], b, acc[mi][ni], 0, 0, 0);
      }
    }
  }
  #pragma unroll
  for (int mi = 0; mi < 2; ++mi) {
    #pragma unroll
    for (int r = 0; r < 4; ++r) {
      int row = wm + mi * 16 + ((lane >> 4) << 2) + r;
      int pid = rowPid[row];
      if (pid < 0) continue;
      float w = rowW[row];
      float* op = out + (size_t)(pid >> 1) * DIM + n0 + wn + (lane & 15);
      #pragma unroll
      for (int ni = 0; ni < 4; ++ni)
        atomicAdd(op + ni * 16, w * acc[mi][ni][r]);
    }
  }
}

extern "C" void kernel_launch(void* const* d_in, const int* in_sizes, int n_in,
                              void* d_out, int out_size, void* d_ws, size_t ws_size,
                              hipStream_t stream)
{
  const float* x  = (const float*)d_in[0];
  const float* Wg = (const float*)d_in[1];
  const float* W1 = (const float*)d_in[2];
  const float* W2 = (const float*)d_in[3];
  const float* W3 = (const float*)d_in[4];
  float* out = (float*)d_out;
  char*  ws  = (char*)d_ws;
  int*   pairCnt = (int*)ws;
  float* auxSum  = (float*)(ws + 64);
  int*   pairIdx = (int*)(ws + 4096);
  float* pairWgt = (float*)(ws + 262144);
  unsigned short* hbuf = (unsigned short*)(ws + ((size_t)1 << 20));
  unsigned short* W1T  = (unsigned short*)(ws + ((size_t)68 << 20));
  unsigned short* W3T  = (unsigned short*)(ws + ((size_t)132 << 20));
  unsigned short* W2T  = (unsigned short*)(ws + ((size_t)196 << 20));
  const size_t WS_NEED = (size_t)260 << 20;

  hipMemsetAsync(ws, 0, 128, stream);
  hipMemsetAsync(d_out, 0, (size_t)out_size * sizeof(float), stream);
  moe_route<<<TOKS / 4, 256, 0, stream>>>(x, Wg, pairCnt, pairIdx, pairWgt, auxSum);
  moe_aux_final<<<1, 1, 0, stream>>>(auxSum, out + (out_size - 1));

  if (ws_size >= WS_NEED) {
    // prep: W1 [E][D][F] -> W1T [E][F][D]; W3 same; W2 [E][F][D] -> W2T [E][D][F]
    cvt_transpose<<<dim3(DIM / 64, NF / 64, NEXP), 256, 0, stream>>>(W1, W1T, DIM, NF);
    cvt_transpose<<<dim3(DIM / 64, NF / 64, NEXP), 256, 0, stream>>>(W3, W3T, DIM, NF);
    cvt_transpose<<<dim3(NF / 64, DIM / 64, NEXP), 256, 0, stream>>>(W2, W2T, NF, DIM);
    moe_ffn1_f<<<(TOKS / BM) * (NF / BN) * NEXP, 512, 0, stream>>>(x, W1T, W3T, pairCnt, pairIdx, hbuf);
    moe_ffn2_f<<<(TOKS / BM) * (DIM / BN) * NEXP, 512, 0, stream>>>(hbuf, W2T, pairCnt, pairIdx, pairWgt, out);
  } else {
    moe_ffn1<<<dim3(TOKS / BM, NF / BN, NEXP), 512, 0, stream>>>(x, W1, W3, pairCnt, pairIdx, hbuf);
    moe_ffn2<<<dim3(TOKS / BM, DIM / BN, NEXP), 512, 0, stream>>>(hbuf, W2, pairCnt, pairIdx, pairWgt, out);
  }
}

// Round 3
// 545.137 us; speedup vs baseline: 5.3096x; 1.1343x over previous
//
#include <hip/hip_runtime.h>

typedef __bf16 bf16x8 __attribute__((ext_vector_type(8)));
typedef float  f32x4  __attribute__((ext_vector_type(4)));

#define TOKS 4096
#define DIM  1024
#define NEXP 8
#define NF   4096
#define CAP  4096   // per-expert pair capacity
#define BM 128
#define BN 128
#define BK 64

typedef __attribute__((address_space(3))) unsigned int as3_u32;
typedef __attribute__((address_space(1))) unsigned int as1_u32;
// async global->LDS, 16B per lane; LDS dest = wave-uniform base + lane*16
__device__ __forceinline__ void gl16(const unsigned short* g, unsigned short* l) {
  __builtin_amdgcn_global_load_lds((as1_u32*)(unsigned long long)g, (as3_u32*)l, 16, 0, 0);
}

__device__ __forceinline__ unsigned short f2bf(float f) {
  unsigned int u = __float_as_uint(f);
  u += 0x7FFFu + ((u >> 16) & 1u);           // round-to-nearest-even
  return (unsigned short)(u >> 16);
}
// fallback-kernel swizzle
__device__ __forceinline__ int swzo(int major) {
  return ((major & 7) ^ ((major >> 3) & 7)) << 3;
}
// XOR 16B-chunk index with row&7; arg/result in elements (8 bf16 chunks)
__device__ __forceinline__ int swz8(int row, int chunk) {
  return (chunk ^ (row & 7)) << 3;
}

// ---------------- routing ----------------
__global__ void moe_route(const float* __restrict__ x, const float* __restrict__ Wg,
                          int* __restrict__ pairCnt, int* __restrict__ pairIdx,
                          float* __restrict__ pairWgt, float* __restrict__ auxSum)
{
  int lane = threadIdx.x & 63;
  int tok  = blockIdx.x * 4 + (threadIdx.x >> 6);
  const float* xr = x + (size_t)tok * DIM;
  float acc[8];
  #pragma unroll
  for (int e = 0; e < 8; ++e) acc[e] = 0.f;
  #pragma unroll
  for (int i = 0; i < 16; ++i) {
    int d = i * 64 + lane;
    float xv = xr[d];
    const float4* wr = (const float4*)(Wg + d * 8);
    float4 wa = wr[0], wb = wr[1];
    acc[0] += xv * wa.x; acc[1] += xv * wa.y; acc[2] += xv * wa.z; acc[3] += xv * wa.w;
    acc[4] += xv * wb.x; acc[5] += xv * wb.y; acc[6] += xv * wb.z; acc[7] += xv * wb.w;
  }
  #pragma unroll
  for (int e = 0; e < 8; ++e) {
    float v = acc[e];
    #pragma unroll
    for (int off = 32; off; off >>= 1) v += __shfl_xor(v, off);
    acc[e] = v;
  }
  if (lane == 0) {
    int e1 = 0; float l1 = acc[0];
    #pragma unroll
    for (int e = 1; e < 8; ++e) if (acc[e] > l1) { l1 = acc[e]; e1 = e; }
    int e2 = -1; float l2 = -3.4e38f;
    #pragma unroll
    for (int e = 0; e < 8; ++e) if (e != e1 && acc[e] > l2) { l2 = acc[e]; e2 = e; }
    float r  = expf(l2 - l1);
    float w1 = 1.f / (1.f + r);
    float w2 = r / (1.f + r);
    int s1 = atomicAdd(&pairCnt[e1], 1);
    pairIdx[e1 * CAP + s1] = tok * 2;     pairWgt[e1 * CAP + s1] = w1;
    int s2 = atomicAdd(&pairCnt[e2], 1);
    pairIdx[e2 * CAP + s2] = tok * 2 + 1; pairWgt[e2 * CAP + s2] = w2;
    float m = 0.f;
    #pragma unroll
    for (int e = 0; e < 8; ++e) m += acc[e];
    m *= 0.125f;
    float v = 0.f;
    #pragma unroll
    for (int e = 0; e < 8; ++e) { float dd = acc[e] - m; v += dd * dd; }
    atomicAdd(auxSum, v * (1.f / 7.f));
  }
}

__global__ void moe_aux_final(const float* __restrict__ auxSum, float* __restrict__ outScalar) {
  *outScalar = auxSum[0] * (1.f / (float)TOKS);
}

// ---------------- x: fp32 -> bf16 ----------------
__global__ __launch_bounds__(256) void cvt_x(const float* __restrict__ in,
                                             unsigned short* __restrict__ o)
{
  int i = (blockIdx.x * 256 + threadIdx.x) * 16;
  const float4* s = (const float4*)(in + i);
  float4 a = s[0], b = s[1], c = s[2], d = s[3];
  union { unsigned short u[8]; uint4 q; } p0, p1;
  p0.u[0]=f2bf(a.x); p0.u[1]=f2bf(a.y); p0.u[2]=f2bf(a.z); p0.u[3]=f2bf(a.w);
  p0.u[4]=f2bf(b.x); p0.u[5]=f2bf(b.y); p0.u[6]=f2bf(b.z); p0.u[7]=f2bf(b.w);
  p1.u[0]=f2bf(c.x); p1.u[1]=f2bf(c.y); p1.u[2]=f2bf(c.z); p1.u[3]=f2bf(c.w);
  p1.u[4]=f2bf(d.x); p1.u[5]=f2bf(d.y); p1.u[6]=f2bf(d.z); p1.u[7]=f2bf(d.w);
  *(uint4*)(o + i)     = p0.q;
  *(uint4*)(o + i + 8) = p1.q;
}

// ---------------- weight prep: fp32 [E][R][C] -> bf16 [E][C][R] ----------------
__global__ __launch_bounds__(256) void cvt_transpose(
    const float* __restrict__ in, unsigned short* __restrict__ outp, int R, int C)
{
  __shared__ unsigned short tile[64 * 72];
  int e  = blockIdx.z;
  int r0 = blockIdx.x * 64, c0 = blockIdx.y * 64;
  const float*    ine  = in   + (size_t)e * R * C;
  unsigned short* oute = outp + (size_t)e * R * C;
  int t = threadIdx.x;
  int r = t >> 2, cs = (t & 3) * 16;
  const float4* src = (const float4*)(ine + (size_t)(r0 + r) * C + c0 + cs);
  #pragma unroll
  for (int j = 0; j < 4; ++j) {
    float4 v = src[j];
    tile[(cs + j * 4 + 0) * 72 + r] = f2bf(v.x);
    tile[(cs + j * 4 + 1) * 72 + r] = f2bf(v.y);
    tile[(cs + j * 4 + 2) * 72 + r] = f2bf(v.z);
    tile[(cs + j * 4 + 3) * 72 + r] = f2bf(v.w);
  }
  __syncthreads();
  int c = t >> 2, rs = (t & 3) * 16;
  uint4 o0 = *(const uint4*)&tile[c * 72 + rs];
  uint4 o1 = *(const uint4*)&tile[c * 72 + rs + 8];
  unsigned short* dst = oute + (size_t)(c0 + c) * R + r0 + rs;
  *(uint4*)dst       = o0;
  *(uint4*)(dst + 8) = o1;
}

// ---------------- FFN1 (global_load_lds staging): h = silu(x@W1) * (x@W3) ----------------
__global__ __launch_bounds__(512) void moe_ffn1_g(
    const unsigned short* __restrict__ xbf, const unsigned short* __restrict__ W1T,
    const unsigned short* __restrict__ W3T,
    const int* __restrict__ pairCnt, const int* __restrict__ pairIdx,
    unsigned short* __restrict__ hbuf)
{
  // bid bits: [0:3)=n_low(XCD), [3:8)=m, [8:10)=n_high, [10:13)=e
  int bid = blockIdx.x;
  int m_t = (bid >> 3) & 31;
  int n_t = (bid & 7) | (((bid >> 8) & 3) << 3);
  int e   = bid >> 10;
  int cnt = pairCnt[e];
  int m0  = m_t * BM;
  if (m0 >= cnt) return;
  int n0  = n_t * BN;
  __shared__ __attribute__((aligned(16))) unsigned short As[BM * BK];
  __shared__ __attribute__((aligned(16))) unsigned short B1s[BN * BK];
  __shared__ __attribute__((aligned(16))) unsigned short B3s[BN * BK];
  __shared__ int rowPid[BM];
  int tid = threadIdx.x, lane = tid & 63, wid = tid >> 6;
  if (tid < BM) {
    int gi = m0 + tid;
    rowPid[tid] = (gi < cnt) ? pairIdx[e * CAP + gi] : -1;
  }
  const unsigned short* W1e = W1T + (size_t)e * NF * DIM + (size_t)n0 * DIM;
  const unsigned short* W3e = W3T + (size_t)e * NF * DIM + (size_t)n0 * DIM;
  f32x4 zero = {0.f, 0.f, 0.f, 0.f};
  f32x4 acc1[2][4], acc2[2][4];
  #pragma unroll
  for (int mi = 0; mi < 2; ++mi)
    #pragma unroll
    for (int ni = 0; ni < 4; ++ni) { acc1[mi][ni] = zero; acc2[mi][ni] = zero; }
  int wm = (wid >> 1) * 32, wn = (wid & 1) * 64;
  __syncthreads();   // rowPid visible

  // per-lane staging sources (wave covers rows wid*16 .. wid*16+15)
  int r0a = wid * 16 + (lane >> 3), r1a = r0a + 8;
  int p0 = rowPid[r0a], p1 = rowPid[r1a];
  size_t tk0 = (size_t)((p0 >= 0) ? (p0 >> 1) : 0);
  size_t tk1 = (size_t)((p1 >= 0) ? (p1 >> 1) : 0);
  int ch0 = ((lane & 7) ^ (r0a & 7)) * 8;
  int ch1 = ((lane & 7) ^ (r1a & 7)) * 8;
  const unsigned short* gA0  = xbf + tk0 * DIM + ch0;
  const unsigned short* gA1  = xbf + tk1 * DIM + ch1;
  const unsigned short* gB10 = W1e + (size_t)r0a * DIM + ch0;
  const unsigned short* gB11 = W1e + (size_t)r1a * DIM + ch1;
  const unsigned short* gB30 = W3e + (size_t)r0a * DIM + ch0;
  const unsigned short* gB31 = W3e + (size_t)r1a * DIM + ch1;
  unsigned short* lA0  = &As [(wid * 16) * BK];
  unsigned short* lA1  = &As [(wid * 16 + 8) * BK];
  unsigned short* lB10 = &B1s[(wid * 16) * BK];
  unsigned short* lB11 = &B1s[(wid * 16 + 8) * BK];
  unsigned short* lB30 = &B3s[(wid * 16) * BK];
  unsigned short* lB31 = &B3s[(wid * 16 + 8) * BK];

  for (int kt = 0; kt < DIM; kt += BK) {
    gl16(gA0 + kt, lA0);  gl16(gA1 + kt, lA1);
    gl16(gB10 + kt, lB10); gl16(gB11 + kt, lB11);
    gl16(gB30 + kt, lB30); gl16(gB31 + kt, lB31);
    __syncthreads();
    #pragma unroll
    for (int ks = 0; ks < 2; ++ks) {
      int kc = ks * 4 + (lane >> 4);   // 16B chunk along K
      bf16x8 af[2];
      #pragma unroll
      for (int mi = 0; mi < 2; ++mi) {
        int row = wm + mi * 16 + (lane & 15);
        af[mi] = *(const bf16x8*)(&As[row * BK + swz8(row, kc)]);
      }
      #pragma unroll
      for (int ni = 0; ni < 4; ++ni) {
        int f = wn + ni * 16 + (lane & 15);
        bf16x8 b1 = *(const bf16x8*)(&B1s[f * BK + swz8(f, kc)]);
        bf16x8 b3 = *(const bf16x8*)(&B3s[f * BK + swz8(f, kc)]);
        #pragma unroll
        for (int mi = 0; mi < 2; ++mi) {
          acc1[mi][ni] = __builtin_amdgcn_mfma_f32_16x16x32_bf16(af[mi], b1, acc1[mi][ni], 0, 0, 0);
          acc2[mi][ni] = __builtin_amdgcn_mfma_f32_16x16x32_bf16(af[mi], b3, acc2[mi][ni], 0, 0, 0);
        }
      }
    }
    __syncthreads();
  }
  #pragma unroll
  for (int mi = 0; mi < 2; ++mi) {
    #pragma unroll
    for (int r = 0; r < 4; ++r) {
      int row = wm + mi * 16 + ((lane >> 4) << 2) + r;
      int pid = rowPid[row];
      if (pid < 0) continue;
      size_t hb = (size_t)pid * NF + n0 + wn + (lane & 15);
      #pragma unroll
      for (int ni = 0; ni < 4; ++ni) {
        float a = acc1[mi][ni][r];
        float g = acc2[mi][ni][r];
        float s = 1.f / (1.f + __expf(-a));
        hbuf[hb + ni * 16] = f2bf(a * s * g);
      }
    }
  }
}

// ---------------- FFN2 (global_load_lds staging): out[tok] += w * (h @ W2) ----------------
__global__ __launch_bounds__(512) void moe_ffn2_g(
    const unsigned short* __restrict__ hbuf, const unsigned short* __restrict__ W2T,
    const int* __restrict__ pairCnt, const int* __restrict__ pairIdx,
    const float* __restrict__ pairWgt, float* __restrict__ out)
{
  // bid bits: [0:3)=n(XCD), [3:8)=m, [8:11)=e
  int bid = blockIdx.x;
  int n_t = bid & 7;
  int m_t = (bid >> 3) & 31;
  int e   = bid >> 8;
  int cnt = pairCnt[e];
  int m0  = m_t * BM;
  if (m0 >= cnt) return;
  int n0  = n_t * BN;
  __shared__ __attribute__((aligned(16))) unsigned short As[BM * BK];
  __shared__ __attribute__((aligned(16))) unsigned short Bs[BN * BK];
  __shared__ int   rowPid[BM];
  __shared__ float rowW[BM];
  int tid = threadIdx.x, lane = tid & 63, wid = tid >> 6;
  if (tid < BM) {
    int gi = m0 + tid;
    if (gi < cnt) { rowPid[tid] = pairIdx[e * CAP + gi]; rowW[tid] = pairWgt[e * CAP + gi]; }
    else          { rowPid[tid] = -1;                    rowW[tid] = 0.f; }
  }
  const unsigned short* W2e = W2T + (size_t)e * DIM * NF + (size_t)n0 * NF;
  f32x4 zero = {0.f, 0.f, 0.f, 0.f};
  f32x4 acc[2][4];
  #pragma unroll
  for (int mi = 0; mi < 2; ++mi)
    #pragma unroll
    for (int ni = 0; ni < 4; ++ni) acc[mi][ni] = zero;
  int wm = (wid >> 1) * 32, wn = (wid & 1) * 64;
  __syncthreads();

  int r0a = wid * 16 + (lane >> 3), r1a = r0a + 8;
  int p0 = rowPid[r0a], p1 = rowPid[r1a];
  size_t h0 = (size_t)((p0 >= 0) ? p0 : 0);
  size_t h1 = (size_t)((p1 >= 0) ? p1 : 0);
  int ch0 = ((lane & 7) ^ (r0a & 7)) * 8;
  int ch1 = ((lane & 7) ^ (r1a & 7)) * 8;
  const unsigned short* gA0 = hbuf + h0 * NF + ch0;
  const unsigned short* gA1 = hbuf + h1 * NF + ch1;
  const unsigned short* gB0 = W2e + (size_t)r0a * NF + ch0;
  const unsigned short* gB1 = W2e + (size_t)r1a * NF + ch1;
  unsigned short* lA0 = &As[(wid * 16) * BK];
  unsigned short* lA1 = &As[(wid * 16 + 8) * BK];
  unsigned short* lB0 = &Bs[(wid * 16) * BK];
  unsigned short* lB1 = &Bs[(wid * 16 + 8) * BK];

  for (int kt = 0; kt < NF; kt += BK) {
    gl16(gA0 + kt, lA0); gl16(gA1 + kt, lA1);
    gl16(gB0 + kt, lB0); gl16(gB1 + kt, lB1);
    __syncthreads();
    #pragma unroll
    for (int ks = 0; ks < 2; ++ks) {
      int kc = ks * 4 + (lane >> 4);
      bf16x8 af[2];
      #pragma unroll
      for (int mi = 0; mi < 2; ++mi) {
        int row = wm + mi * 16 + (lane & 15);
        af[mi] = *(const bf16x8*)(&As[row * BK + swz8(row, kc)]);
      }
      #pragma unroll
      for (int ni = 0; ni < 4; ++ni) {
        int dc = wn + ni * 16 + (lane & 15);
        bf16x8 b = *(const bf16x8*)(&Bs[dc * BK + swz8(dc, kc)]);
        #pragma unroll
        for (int mi = 0; mi < 2; ++mi)
          acc[mi][ni] = __builtin_amdgcn_mfma_f32_16x16x32_bf16(af[mi], b, acc[mi][ni], 0, 0, 0);
      }
    }
    __syncthreads();
  }
  #pragma unroll
  for (int mi = 0; mi < 2; ++mi) {
    #pragma unroll
    for (int r = 0; r < 4; ++r) {
      int row = wm + mi * 16 + ((lane >> 4) << 2) + r;
      int pid = rowPid[row];
      if (pid < 0) continue;
      float w = rowW[row];
      float* op = out + (size_t)(pid >> 1) * DIM + n0 + wn + (lane & 15);
      #pragma unroll
      for (int ni = 0; ni < 4; ++ni)
        atomicAdd(op + ni * 16, w * acc[mi][ni][r]);
    }
  }
}

// ================= fallback (fp32 weights in-kernel) =================
__global__ __launch_bounds__(512) void moe_ffn1(
    const float* __restrict__ x, const float* __restrict__ W1, const float* __restrict__ W3,
    const int* __restrict__ pairCnt, const int* __restrict__ pairIdx,
    unsigned short* __restrict__ hbuf)
{
  int e   = blockIdx.z;
  int cnt = pairCnt[e];
  int m0  = blockIdx.x * BM;
  if (m0 >= cnt) return;
  int n0  = blockIdx.y * BN;
  __shared__ __attribute__((aligned(16))) unsigned short As[BM * BK];
  __shared__ __attribute__((aligned(16))) unsigned short B1s[BN * BK];
  __shared__ __attribute__((aligned(16))) unsigned short B3s[BN * BK];
  __shared__ int rowPid[BM];
  int tid = threadIdx.x;
  if (tid < BM) {
    int gi = m0 + tid;
    rowPid[tid] = (gi < cnt) ? pairIdx[e * CAP + gi] : -1;
  }
  const float* W1e = W1 + (size_t)e * DIM * NF;
  const float* W3e = W3 + (size_t)e * DIM * NF;
  f32x4 zero = {0.f, 0.f, 0.f, 0.f};
  f32x4 acc1[2][4], acc2[2][4];
  #pragma unroll
  for (int mi = 0; mi < 2; ++mi)
    #pragma unroll
    for (int ni = 0; ni < 4; ++ni) { acc1[mi][ni] = zero; acc2[mi][ni] = zero; }
  int lane = tid & 63, wid = tid >> 6;
  int wm = (wid >> 1) * 32, wn = (wid & 1) * 64;

  for (int kt = 0; kt < DIM; kt += BK) {
    __syncthreads();
    #pragma unroll
    for (int it = 0; it < 4; ++it) {
      int row = it * 32 + (tid >> 4);
      int dq  = tid & 15;
      int pid = rowPid[row];
      int tk  = (pid >= 0) ? (pid >> 1) : 0;
      float4 v = *(const float4*)(x + (size_t)tk * DIM + kt + dq * 4);
      ushort4 b; b.x = f2bf(v.x); b.y = f2bf(v.y); b.z = f2bf(v.z); b.w = f2bf(v.w);
      *(ushort4*)(&As[row * BK + ((dq * 4) ^ swzo(row))]) = b;
    }
    #pragma unroll
    for (int it = 0; it < 4; ++it) {
      int d  = it * 16 + (tid >> 5);
      int fq = tid & 31;
      size_t go = (size_t)(kt + d) * NF + n0 + fq * 4;
      float4 v1 = *(const float4*)(W1e + go);
      float4 v3 = *(const float4*)(W3e + go);
      const float* p1 = (const float*)&v1;
      const float* p3 = (const float*)&v3;
      #pragma unroll
      for (int i = 0; i < 4; ++i) {
        int f   = fq * 4 + i;
        int idx = f * BK + (d ^ swzo(f));
        B1s[idx] = f2bf(p1[i]);
        B3s[idx] = f2bf(p3[i]);
      }
    }
    __syncthreads();
    #pragma unroll
    for (int ks = 0; ks < 2; ++ks) {
      int kb = ks * 32 + ((lane >> 4) << 3);
      bf16x8 af[2];
      #pragma unroll
      for (int mi = 0; mi < 2; ++mi) {
        int row = wm + mi * 16 + (lane & 15);
        af[mi] = *(const bf16x8*)(&As[row * BK + (kb ^ swzo(row))]);
      }
      #pragma unroll
      for (int ni = 0; ni < 4; ++ni) {
        int f = wn + ni * 16 + (lane & 15);
        bf16x8 b1 = *(const bf16x8*)(&B1s[f * BK + (kb ^ swzo(f))]);
        bf16x8 b3 = *(const bf16x8*)(&B3s[f * BK + (kb ^ swzo(f))]);
        #pragma unroll
        for (int mi = 0; mi < 2; ++mi) {
          acc1[mi][ni] = __builtin_amdgcn_mfma_f32_16x16x32_bf16(af[mi], b1, acc1[mi][ni], 0, 0, 0);
          acc2[mi][ni] = __builtin_amdgcn_mfma_f32_16x16x32_bf16(af[mi], b3, acc2[mi][ni], 0, 0, 0);
        }
      }
    }
  }
  #pragma unroll
  for (int mi = 0; mi < 2; ++mi) {
    #pragma unroll
    for (int r = 0; r < 4; ++r) {
      int row = wm + mi * 16 + ((lane >> 4) << 2) + r;
      int pid = rowPid[row];
      if (pid < 0) continue;
      size_t hb = (size_t)pid * NF + n0 + wn + (lane & 15);
      #pragma unroll
      for (int ni = 0; ni < 4; ++ni) {
        float a = acc1[mi][ni][r];
        float g = acc2[mi][ni][r];
        float s = 1.f / (1.f + __expf(-a));
        hbuf[hb + ni * 16] = f2bf(a * s * g);
      }
    }
  }
}

__global__ __launch_bounds__(512) void moe_ffn2(
    const unsigned short* __restrict__ hbuf, const float* __restrict__ W2,
    const int* __restrict__ pairCnt, const int* __restrict__ pairIdx,
    const float* __restrict__ pairWgt, float* __restrict__ out)
{
  int e   = blockIdx.z;
  int cnt = pairCnt[e];
  int m0  = blockIdx.x * BM;
  if (m0 >= cnt) return;
  int n0  = blockIdx.y * BN;
  __shared__ __attribute__((aligned(16))) unsigned short As[BM * BK];
  __shared__ __attribute__((aligned(16))) unsigned short Bs[BN * BK];
  __shared__ int   rowPid[BM];
  __shared__ float rowW[BM];
  int tid = threadIdx.x;
  if (tid < BM) {
    int gi = m0 + tid;
    if (gi < cnt) { rowPid[tid] = pairIdx[e * CAP + gi]; rowW[tid] = pairWgt[e * CAP + gi]; }
    else          { rowPid[tid] = -1;                    rowW[tid] = 0.f; }
  }
  const float* W2e = W2 + (size_t)e * NF * DIM;
  f32x4 zero = {0.f, 0.f, 0.f, 0.f};
  f32x4 acc[2][4];
  #pragma unroll
  for (int mi = 0; mi < 2; ++mi)
    #pragma unroll
    for (int ni = 0; ni < 4; ++ni) acc[mi][ni] = zero;
  int lane = tid & 63, wid = tid >> 6;
  int wm = (wid >> 1) * 32, wn = (wid & 1) * 64;

  for (int kt = 0; kt < NF; kt += BK) {
    __syncthreads();
    #pragma unroll
    for (int it = 0; it < 2; ++it) {
      int row = it * 64 + (tid >> 3);
      int c8  = tid & 7;
      int pid = rowPid[row];
      int pr  = (pid >= 0) ? pid : 0;
      uint4 v = *(const uint4*)(hbuf + (size_t)pr * NF + kt + c8 * 8);
      *(uint4*)(&As[row * BK + ((c8 * 8) ^ swzo(row))]) = v;
    }
    #pragma unroll
    for (int it = 0; it < 4; ++it) {
      int fk = it * 16 + (tid >> 5);
      int dq = tid & 31;
      float4 v = *(const float4*)(W2e + (size_t)(kt + fk) * DIM + n0 + dq * 4);
      const float* p = (const float*)&v;
      #pragma unroll
      for (int i = 0; i < 4; ++i) {
        int dc = dq * 4 + i;
        Bs[dc * BK + (fk ^ swzo(dc))] = f2bf(p[i]);
      }
    }
    __syncthreads();
    #pragma unroll
    for (int ks = 0; ks < 2; ++ks) {
      int kb = ks * 32 + ((lane >> 4) << 3);
      bf16x8 af[2];
      #pragma unroll
      for (int mi = 0; mi < 2; ++mi) {
        int row = wm + mi * 16 + (lane & 15);
        af[mi] = *(const bf16x8*)(&As[row * BK + (kb ^ swzo(row))]);
      }
      #pragma unroll
      for (int ni = 0; ni < 4; ++ni) {
        int dc = wn + ni * 16 + (lane & 15);
        bf16x8 b = *(const bf16x8*)(&Bs[dc * BK + (kb ^ swzo(dc))]);
        #pragma unroll
        for (int mi = 0; mi < 2; ++mi)
          acc[mi][ni] = __builtin_amdgcn_mfma_f32_16x16x32_bf16(af[mi], b, acc[mi][ni], 0, 0, 0);
      }
    }
  }
  #pragma unroll
  for (int mi = 0; mi < 2; ++mi) {
    #pragma unroll
    for (int r = 0; r < 4; ++r) {
      int row = wm + mi * 16 + ((lane >> 4) << 2) + r;
      int pid = rowPid[row];
      if (pid < 0) continue;
      float w = rowW[row];
      float* op = out + (size_t)(pid >> 1) * DIM + n0 + wn + (lane & 15);
      #pragma unroll
      for (int ni = 0; ni < 4; ++ni)
        atomicAdd(op + ni * 16, w * acc[mi][ni][r]);
    }
  }
}

extern "C" void kernel_launch(void* const* d_in, const int* in_sizes, int n_in,
                              void* d_out, int out_size, void* d_ws, size_t ws_size,
                              hipStream_t stream)
{
  const float* x  = (const float*)d_in[0];
  const float* Wg = (const float*)d_in[1];
  const float* W1 = (const float*)d_in[2];
  const float* W2 = (const float*)d_in[3];
  const float* W3 = (const float*)d_in[4];
  float* out = (float*)d_out;
  char*  ws  = (char*)d_ws;
  int*   pairCnt = (int*)ws;
  float* auxSum  = (float*)(ws + 64);
  int*   pairIdx = (int*)(ws + 4096);
  float* pairWgt = (float*)(ws + 262144);
  // fast-path layout (from 1 MiB): xbf 8M, hbuf 64M, W1T 64M, W3T 64M, W2T 64M
  unsigned short* xbf  = (unsigned short*)(ws + ((size_t)1 << 20));
  unsigned short* hbuf = (unsigned short*)(ws + ((size_t)9 << 20));
  unsigned short* W1T  = (unsigned short*)(ws + ((size_t)73 << 20));
  unsigned short* W3T  = (unsigned short*)(ws + ((size_t)137 << 20));
  unsigned short* W2T  = (unsigned short*)(ws + ((size_t)201 << 20));
  const size_t WS_NEED = (size_t)265 << 20;

  hipMemsetAsync(ws, 0, 128, stream);
  hipMemsetAsync(d_out, 0, (size_t)out_size * sizeof(float), stream);
  moe_route<<<TOKS / 4, 256, 0, stream>>>(x, Wg, pairCnt, pairIdx, pairWgt, auxSum);
  moe_aux_final<<<1, 1, 0, stream>>>(auxSum, out + (out_size - 1));

  if (ws_size >= WS_NEED) {
    cvt_x<<<TOKS * DIM / (256 * 16), 256, 0, stream>>>(x, xbf);
    cvt_transpose<<<dim3(DIM / 64, NF / 64, NEXP), 256, 0, stream>>>(W1, W1T, DIM, NF);
    cvt_transpose<<<dim3(DIM / 64, NF / 64, NEXP), 256, 0, stream>>>(W3, W3T, DIM, NF);
    cvt_transpose<<<dim3(NF / 64, DIM / 64, NEXP), 256, 0, stream>>>(W2, W2T, NF, DIM);
    moe_ffn1_g<<<(TOKS / BM) * (NF / BN) * NEXP, 512, 0, stream>>>(xbf, W1T, W3T, pairCnt, pairIdx, hbuf);
    moe_ffn2_g<<<(TOKS / BM) * (DIM / BN) * NEXP, 512, 0, stream>>>(hbuf, W2T, pairCnt, pairIdx, pairWgt, out);
  } else {
    moe_ffn1<<<dim3(TOKS / BM, NF / BN, NEXP), 512, 0, stream>>>(x, W1, W3, pairCnt, pairIdx, hbuf);
    moe_ffn2<<<dim3(TOKS / BM, DIM / BN, NEXP), 512, 0, stream>>>(hbuf, W2, pairCnt, pairIdx, pairWgt, out);
  }
}